// Round 9
// baseline (183.047 us; speedup 1.0000x reference)
//
#include <hip/hip_runtime.h>

#define N_NODES 100000
#define N_EDGES 1600000
#define EMBED_DIM 64

#define RPB 256                                   // rows per bucket
#define NBKT ((N_NODES + RPB - 1) / RPB)          // 391
#define CAP 4608                                  // slots per bucket (mean 4092, +8 sigma)
#define TILE 4096                                 // edges per binA block
#define NTILE ((N_EDGES + TILE - 1) / TILE)       // 391
#define OVCAP 8192                                // overflow backstop

#define BG_THREADS 1024
#define EPT ((CAP + BG_THREADS - 1) / BG_THREADS) // 5 edges/thread in registers

// ---------- pass A: tile counting-sort, DIRECT global write (no LDS stage) ----------
// r6 lesson nuance: scattered 8B writes are only poisonous when a line's
// writers are spread across blocks/time (r6: 100MB WRITE). Here a bucket's
// per-tile segment (~10.5 consecutive slots) is written by ONE block within
// a tight window -> L2 coalesces. Dropping stage[]/dg[]/flush removes 48KB
// LDS, 2 barriers, and one LDS round-trip; rows[] cached in registers
// between passes removes a 6.4MB re-read.
__global__ __launch_bounds__(512) void k_binA(const int* __restrict__ rows,
                                              const int* __restrict__ cols,
                                              const float* __restrict__ vals,
                                              int* __restrict__ gcur,
                                              int2* __restrict__ packed,
                                              int* __restrict__ ov_cnt,
                                              int4* __restrict__ ov) {
    __shared__ int hist[NBKT];
    __shared__ int off[NBKT];
    __shared__ int cur[NBKT];
    __shared__ int gbase[NBKT];
    __shared__ int wsum[8];
    const int tid = threadIdx.x;
    const int lane = tid & 63;
    const int wid = tid >> 6;      // 0..7
    const int e0 = blockIdx.x * TILE;

    for (int i = tid; i < NBKT; i += 512) hist[i] = 0;
    __syncthreads();

    // pass 1: histogram; cache rows in registers
    int rr[8];
#pragma unroll
    for (int jj = 0; jj < 8; ++jj) {
        int e = e0 + tid + jj * 512;
        rr[jj] = (e < N_EDGES) ? rows[e] : -1;
        if (rr[jj] >= 0) atomicAdd(&hist[rr[jj] >> 8], 1);
    }
    __syncthreads();

    // exclusive scan of hist[0..NBKT-1]: per-wave shfl scan + wave-offset combine
    int v = (tid < NBKT) ? hist[tid] : 0;
    int incl = v;
    for (int o = 1; o < 64; o <<= 1) {
        int t = __shfl_up(incl, o, 64);
        if (lane >= o) incl += t;
    }
    if (lane == 63) wsum[wid] = incl;
    __syncthreads();
    if (wid == 0 && lane < 8) {
        int s = wsum[lane];
        int si = s;
        for (int o = 1; o < 8; o <<= 1) {
            int t = __shfl_up(si, o, 64);
            if (lane >= o) si += t;
        }
        wsum[lane] = si - s;           // exclusive wave offset
    }
    __syncthreads();
    int excl = incl - v + wsum[wid];
    if (tid < NBKT) { off[tid] = excl; cur[tid] = excl; }

    // bulk global reservation: one atomic per non-empty bucket
    for (int b = tid; b < NBKT; b += 512) {
        int c = hist[b];
        gbase[b] = c ? atomicAdd(&gcur[b], c) : 0;
    }
    __syncthreads();

    // pass 2: direct global placement (segment-dense within this block)
#pragma unroll
    for (int jj = 0; jj < 8; ++jj) {
        int r = rr[jj];
        if (r >= 0) {
            int e = e0 + tid + jj * 512;
            int b = r >> 8;
            int p = atomicAdd(&cur[b], 1);
            int d = gbase[b] + (p - off[b]);
            int c = cols[e];
            int fv = __float_as_int(vals[e]);
            if (d < CAP) {
                packed[(size_t)b * CAP + d] = make_int2(((r & (RPB - 1)) << 17) | c, fv);
            } else {  // overflow backstop (statistically never)
                int ovi = atomicAdd(ov_cnt, 1);
                if (ovi < OVCAP) ov[ovi] = make_int4(r, c, fv, 0);
            }
        }
    }
}

// ---------- fused binB+gather: one block per bucket (verified r8 version) ----------
__global__ __launch_bounds__(BG_THREADS) void k_bg(const float* __restrict__ x,
                                                   const int* __restrict__ gcur,
                                                   const int2* __restrict__ packed,
                                                   float* __restrict__ out) {
    __shared__ int2 stage[CAP];    // 36 KB
    __shared__ int h[RPB];
    __shared__ int ofs[RPB];
    __shared__ int cur[RPB];
    __shared__ int wsum[4];
    const int b = blockIdx.x;
    const int tid = threadIdx.x;
    const int lane = tid & 63;
    const int wid = tid >> 6;      // 0..15
    int n = gcur[b];
    if (n > CAP) n = CAP;
    const int base = b * CAP;

    if (tid < RPB) h[tid] = 0;
    __syncthreads();

    // load edges into registers + histogram rows
    int2 ereg[EPT];
    int lr[EPT];
#pragma unroll
    for (int jj = 0; jj < EPT; ++jj) {
        int j = tid + jj * BG_THREADS;
        lr[jj] = -1;
        if (j < n) {
            int2 e = packed[base + j];
            ereg[jj] = e;
            int r = ((unsigned)e.x) >> 17;
            lr[jj] = r;
            atomicAdd(&h[r], 1);
        }
    }
    __syncthreads();

    // exclusive scan h[0..255] (waves 0..3)
    int hv = (tid < RPB) ? h[tid] : 0;
    int incl = hv;
    for (int o = 1; o < 64; o <<= 1) {
        int t = __shfl_up(incl, o, 64);
        if (lane >= o) incl += t;
    }
    if (tid < RPB && lane == 63) wsum[wid] = incl;
    __syncthreads();
    if (wid == 0 && lane < 4) {
        int s = wsum[lane];
        int si = s;
        for (int o = 1; o < 4; o <<= 1) {
            int t = __shfl_up(si, o, 64);
            if (lane >= o) si += t;
        }
        wsum[lane] = si - s;
    }
    __syncthreads();
    if (tid < RPB) {
        int o2 = incl - hv + wsum[wid];
        ofs[tid] = o2;
        cur[tid] = o2;
    }
    __syncthreads();

    // place row-sorted into LDS (source = registers -> no RAW hazard)
#pragma unroll
    for (int jj = 0; jj < EPT; ++jj) {
        if (lr[jj] >= 0) {
            int p = atomicAdd(&cur[lr[jj]], 1);
            stage[p] = ereg[jj];
        }
    }
    __syncthreads();

    // gather: wave wid handles rows wid*16 .. wid*16+15
    const int half = lane >> 5;    // 0: even edges, 1: odd edges
    const int hl = lane & 31;      // dim-pair index
    const float2* __restrict__ x2 = (const float2*)x;
    for (int i = 0; i < 16; ++i) {
        int r = wid * 16 + i;
        int grow = b * RPB + r;
        if (grow >= N_NODES) break;
        int deg = h[r];
        int beg = ofs[r];
        float ax = 0.f, ay = 0.f;
        for (int j0 = 0; j0 < deg; j0 += 16) {
            float vv[8];
            float2 xv[8];
#pragma unroll
            for (int k = 0; k < 8; ++k) {
                int j = j0 + 2 * k + half;
                int2 e = (j < deg) ? stage[beg + j] : make_int2(0, 0);
                vv[k] = __int_as_float(e.y);               // 0 for pad
                xv[k] = x2[(e.x & 0x1FFFF) * 32 + hl];     // x[0] row for pad
            }
#pragma unroll
            for (int k = 0; k < 8; ++k) {
                ax += vv[k] * xv[k].x;
                ay += vv[k] * xv[k].y;
            }
        }
        ax += __shfl_xor(ax, 32);
        ay += __shfl_xor(ay, 32);
        if (half == 0) {
            ((float2*)out)[(size_t)grow * 32 + hl] = make_float2(ax, ay);
        }
    }
}

// ---------- overflow cleanup (runs after gather; expected n==0) ----------
__global__ __launch_bounds__(256) void k_overflow(const float* __restrict__ x,
                                                  const int* __restrict__ ov_cnt,
                                                  const int4* __restrict__ ov,
                                                  float* __restrict__ out) {
    int n = *ov_cnt;
    if (n > OVCAP) n = OVCAP;
    int lane = threadIdx.x & 63;
    int wglobal = (blockIdx.x * 256 + threadIdx.x) >> 6;
    for (int i = wglobal; i < n; i += 64 * 4) {
        int4 e = ov[i];
        atomicAdd(&out[e.x * EMBED_DIM + lane],
                  __int_as_float(e.z) * x[e.y * EMBED_DIM + lane]);
    }
}

// ---------- fallback (ws too small): atomic scatter ----------
__global__ __launch_bounds__(256) void spmm_scatter_kernel(
    const float* __restrict__ x, const float* __restrict__ vals,
    const int* __restrict__ rows, const int* __restrict__ cols,
    float* __restrict__ out) {
    const int wave_in_block = threadIdx.x >> 6;
    const int lane = threadIdx.x & 63;
    const int e = blockIdx.x * 4 + wave_in_block;
    if (e >= N_EDGES) return;
    const float m = vals[e] * x[cols[e] * EMBED_DIM + lane];
    atomicAdd(&out[rows[e] * EMBED_DIM + lane], m);
}

extern "C" void kernel_launch(void* const* d_in, const int* in_sizes, int n_in,
                              void* d_out, int out_size, void* d_ws, size_t ws_size,
                              hipStream_t stream) {
    const float* x    = (const float*)d_in[0];
    const float* vals = (const float*)d_in[1];
    const int*   rows = (const int*)d_in[2];
    const int*   cols = (const int*)d_in[3];
    float* out = (float*)d_out;

    // ws layout: packed[NBKT*CAP] int2 | ov[OVCAP] int4 | gcur[NBKT] | ov_cnt
    const size_t packed_b = (size_t)NBKT * CAP * 8;         // 14,413,824 (16B-aligned)
    const size_t ov_b     = (size_t)OVCAP * 16;
    const size_t need = packed_b + ov_b + ((size_t)NBKT + 1) * 4;
    if (ws_size < need) {
        hipMemsetAsync(out, 0, (size_t)out_size * sizeof(float), stream);
        spmm_scatter_kernel<<<(N_EDGES + 3) / 4, 256, 0, stream>>>(x, vals, rows, cols, out);
        return;
    }

    int2* packed  = (int2*)d_ws;
    int4* ov      = (int4*)((char*)d_ws + packed_b);
    int*  gcur    = (int*)((char*)d_ws + packed_b + ov_b);
    int*  ov_cnt  = gcur + NBKT;

    // single memset: gcur[NBKT] + ov_cnt adjacent
    hipMemsetAsync(gcur, 0, ((size_t)NBKT + 1) * sizeof(int), stream);

    k_binA<<<NTILE, 512, 0, stream>>>(rows, cols, vals, gcur, packed, ov_cnt, ov);
    k_bg<<<NBKT, BG_THREADS, 0, stream>>>(x, gcur, (const int2*)packed, out);
    k_overflow<<<64, 256, 0, stream>>>(x, ov_cnt, ov, out);
}